// Round 20
// baseline (2999.898 us; speedup 1.0000x reference)
//
#include <hip/hip_runtime.h>

// SentimentNet on MI355X — round 20: single-phase MFMA step.
//
// r19 ledger: step 3.66us = TWO (detect->MFMA->barrier->gates) chains.
// r9's single-phase failure mechanism (gates waiting on 8 waves' 1.7us
// serial VALU dots) is gone now that the dot is a ~0.15us MFMA burst.
// Merge the G=0/G=1 phases: one 16x16x32 MFMA set covers all 8 batch
// cols (24 MFMA/step, was 48), ONE barrier/step, gates on tid<128 (one
// (unit,batch) pair each). red parity + tag transitivity (r9/r16-proven)
// replaces the trailing barrier; waves 2-7 overlap gates with the next
// step's tag-wait.

#define S_LEN 500
#define BATCH 64
#define EDIM 512
#define HDIM 512
#define TEAMS 8
#define WGS_PER_TEAM 32
#define TB 8
#define NBLOCKS (TEAMS * WGS_PER_TEAM)
#define NTHREADS 512
#define NSLICE 8
#define SLICE_LEN 63              // 7*63 + 59 = 500

typedef unsigned long long ull;
typedef __attribute__((ext_vector_type(8))) short short8v;
typedef __attribute__((ext_vector_type(4))) float float4v;
typedef __attribute__((ext_vector_type(4))) unsigned int uint4v;

// workspace layout (bytes)
#define XPROJ_BYTES  ((size_t)S_LEN * 2048 * BATCH * 4)   // 262,144,000
#define STATES_OFF   XPROJ_BYTES
#define STATES_BYTES ((size_t)S_LEN * BATCH * HDIM * 4)   // 65,536,000
#define HBUF_OFF     (STATES_OFF + STATES_BYTES)
#define HBUF_BYTES   ((size_t)2 * TEAMS * TB * HDIM * 8)  // 524,288 (ull)
#define PART_OFF     (HBUF_OFF + HBUF_BYTES)
#define PART_BYTES   (4 * S_LEN * BATCH * 4)              // 512,000
#define POOLP_OFF    (PART_OFF + PART_BYTES)
#define POOLP_BYTES  ((size_t)BATCH * NSLICE * HDIM * 4)  // 1,048,576
#define ML_OFF       (POOLP_OFF + POOLP_BYTES)
#define ML_BYTES     (BATCH * NSLICE * 2 * 4)             // 4,096

// ---------------- xproj GEMM (unchanged r16) ----------------
__global__ __launch_bounds__(256) void xproj_gemm(
    const int* __restrict__ idx, const float* __restrict__ emb,
    const float* __restrict__ W_ih, const float* __restrict__ b_ih,
    const float* __restrict__ b_hh, float* __restrict__ xproj) {
  __shared__ float At[16][132];   // [k][g]
  __shared__ float Bt[16][132];   // [k][sb]
  __shared__ int sidx[128];

  const int tid = threadIdx.x;
  const int sb0 = blockIdx.x * 128;
  const int g0  = blockIdx.y * 128;
  if (tid < 128) sidx[tid] = idx[sb0 + tid];

  const int ty = tid >> 4, tx = tid & 15;
  const int ra = tid & 127, pp = tid >> 7;

  float acc[8][8];
#pragma unroll
  for (int i = 0; i < 8; ++i)
#pragma unroll
    for (int j = 0; j < 8; ++j) acc[i][j] = 0.f;

  __syncthreads();

  for (int k0 = 0; k0 < 512; k0 += 16) {
    const float* pa = &W_ih[(size_t)(g0 + ra) * 512 + k0 + 8 * pp];
    float4 a0 = *(const float4*)pa, a1 = *(const float4*)(pa + 4);
    const float* pb = &emb[(size_t)sidx[ra] * 512 + k0 + 8 * pp];
    float4 b0 = *(const float4*)pb, b1 = *(const float4*)(pb + 4);
    At[8*pp+0][ra]=a0.x; At[8*pp+1][ra]=a0.y; At[8*pp+2][ra]=a0.z; At[8*pp+3][ra]=a0.w;
    At[8*pp+4][ra]=a1.x; At[8*pp+5][ra]=a1.y; At[8*pp+6][ra]=a1.z; At[8*pp+7][ra]=a1.w;
    Bt[8*pp+0][ra]=b0.x; Bt[8*pp+1][ra]=b0.y; Bt[8*pp+2][ra]=b0.z; Bt[8*pp+3][ra]=b0.w;
    Bt[8*pp+4][ra]=b1.x; Bt[8*pp+5][ra]=b1.y; Bt[8*pp+6][ra]=b1.z; Bt[8*pp+7][ra]=b1.w;
    __syncthreads();
#pragma unroll
    for (int kk = 0; kk < 16; ++kk) {
      float4 x0 = *(const float4*)&At[kk][ty * 8];
      float4 x1 = *(const float4*)&At[kk][ty * 8 + 4];
      float4 y0 = *(const float4*)&Bt[kk][tx * 8];
      float4 y1 = *(const float4*)&Bt[kk][tx * 8 + 4];
      float av[8] = {x0.x, x0.y, x0.z, x0.w, x1.x, x1.y, x1.z, x1.w};
      float bv[8] = {y0.x, y0.y, y0.z, y0.w, y1.x, y1.y, y1.z, y1.w};
#pragma unroll
      for (int i = 0; i < 8; ++i)
#pragma unroll
        for (int j = 0; j < 8; ++j) acc[i][j] = fmaf(av[i], bv[j], acc[i][j]);
    }
    __syncthreads();
  }
  const int sbb = sb0 + tx * 8;
  const int s  = sbb >> 6;
  const int tm = (sbb & 63) >> 3;
#pragma unroll
  for (int i = 0; i < 8; ++i) {
    const int g = g0 + ty * 8 + i;
    const float bias = b_ih[g] + b_hh[g];
    float* dst = &xproj[(((size_t)s * TEAMS + tm) * 2048 + g) * 8];
    float4 v0 = {acc[i][0] + bias, acc[i][1] + bias, acc[i][2] + bias, acc[i][3] + bias};
    float4 v1 = {acc[i][4] + bias, acc[i][5] + bias, acc[i][6] + bias, acc[i][7] + bias};
    *(float4*)dst = v0;
    *(float4*)(dst + 4) = v1;
  }
}

// ---------------- persistent recurrence (single-phase MFMA step) ----------------
__global__ __launch_bounds__(NTHREADS, 1) void lstm_persistent(
    const float* __restrict__ xproj, const float* __restrict__ W_hh,
    float* __restrict__ states, ull* __restrict__ h_buf) {
  __shared__ float red[2][8][4][16][9];   // [par][wave][j][u][b pad9] 36.9KB? no: 2*8*4*16*9*4=18.4KB
  __shared__ unsigned hT[8][8][66];       // wave-private transpose (packed) 16.9KB

  const int team = blockIdx.x & 7;           // XCD-local teams
  const int wg   = blockIdx.x >> 3;          // 0..31 -> units [16wg, 16wg+16)
  const int tid  = threadIdx.x;
  const int wv   = tid >> 6;                 // wave 0..7 -> k chunk [64wv, 64wv+64)
  const int l    = tid & 63;                 // lane

  const int col = l & 15;                    // MFMA A-row / B-col / D-col
  const int kg  = l >> 4;                    // k-group 0..3

  // ---- A fragments: W_hh split hi/lo bf16, fragment order, reg-stationary
  short8v Ahi[4][2], Alo[4][2];
#pragma unroll
  for (int j = 0; j < 4; ++j)
#pragma unroll
    for (int ks = 0; ks < 2; ++ks) {
      const float* wr = &W_hh[((size_t)(16 * wg + col) + 512 * j) * 512
                              + 64 * wv + 32 * ks + 8 * kg];
      unsigned hw[4], lw[4];
#pragma unroll
      for (int p = 0; p < 4; ++p) {
        float w0 = wr[2 * p], w1 = wr[2 * p + 1];
        unsigned u0 = __float_as_uint(w0), u1 = __float_as_uint(w1);
        hw[p] = (u1 & 0xffff0000u) | (u0 >> 16);
        float l0 = w0 - __uint_as_float(u0 & 0xffff0000u);
        float l1 = w1 - __uint_as_float(u1 & 0xffff0000u);
        lw[p] = (__float_as_uint(l1) & 0xffff0000u) | (__float_as_uint(l0) >> 16);
      }
      uint4v ph = {hw[0], hw[1], hw[2], hw[3]};
      uint4v pl = {lw[0], lw[1], lw[2], lw[3]};
      Ahi[j][ks] = __builtin_bit_cast(short8v, ph);
      Alo[j][ks] = __builtin_bit_cast(short8v, pl);
    }

  // gate identity: tid<128, one (unit, batch) pair per thread
  const int gu = tid & 15, gb = (tid >> 4) & 7;   // gb valid for tid<128
  const int unit = 16 * wg + gu;
  float c_state = 0.f;
  const float* xpbase = xproj + (size_t)(16 * wg + gu) * 8 + gb;

  const bool bact = (col < 8);               // B/D-active lane (batch col)

  for (int s = 0; s < S_LEN; ++s) {
    const int par = s & 1, par2 = (s + 1) & 1;

    // gate threads prefetch this step's 4 xproj values (coalesced 512B)
    float xv0, xv1, xv2, xv3;
    if (tid < 128) {
      const float* p = xpbase + ((size_t)s * TEAMS + team) * (2048 * 8);
      xv0 = p[0]; xv1 = p[512 * 8]; xv2 = p[1024 * 8]; xv3 = p[1536 * 8];
    }

    float4v acc[4];
#pragma unroll
    for (int j = 0; j < 4; ++j) acc[j] = (float4v){0.f, 0.f, 0.f, 0.f};

    if (s > 0) {
      // tag-load all 8 batches' h, coalesced (lane=unit layout)
      const ull* hb0 = h_buf + (((size_t)par * TEAMS + team) * TB) * HDIM
                       + (size_t)64 * wv + l;
      ull r0, r1, r2, r3, r4, r5, r6, r7;
      int spins = 0;
      for (;;) {
        r0 = __hip_atomic_load(hb0 + 0 * HDIM, __ATOMIC_RELAXED, __HIP_MEMORY_SCOPE_AGENT);
        r1 = __hip_atomic_load(hb0 + 1 * HDIM, __ATOMIC_RELAXED, __HIP_MEMORY_SCOPE_AGENT);
        r2 = __hip_atomic_load(hb0 + 2 * HDIM, __ATOMIC_RELAXED, __HIP_MEMORY_SCOPE_AGENT);
        r3 = __hip_atomic_load(hb0 + 3 * HDIM, __ATOMIC_RELAXED, __HIP_MEMORY_SCOPE_AGENT);
        r4 = __hip_atomic_load(hb0 + 4 * HDIM, __ATOMIC_RELAXED, __HIP_MEMORY_SCOPE_AGENT);
        r5 = __hip_atomic_load(hb0 + 5 * HDIM, __ATOMIC_RELAXED, __HIP_MEMORY_SCOPE_AGENT);
        r6 = __hip_atomic_load(hb0 + 6 * HDIM, __ATOMIC_RELAXED, __HIP_MEMORY_SCOPE_AGENT);
        r7 = __hip_atomic_load(hb0 + 7 * HDIM, __ATOMIC_RELAXED, __HIP_MEMORY_SCOPE_AGENT);
        bool ok = ((int)(r0 >> 32) == s) & ((int)(r1 >> 32) == s) &
                  ((int)(r2 >> 32) == s) & ((int)(r3 >> 32) == s) &
                  ((int)(r4 >> 32) == s) & ((int)(r5 >> 32) == s) &
                  ((int)(r6 >> 32) == s) & ((int)(r7 >> 32) == s);
        if (__all(ok)) break;
        __builtin_amdgcn_s_sleep(1);
        if (++spins > (1 << 18)) break;      // hang guard only
      }
      // intra-wave LDS transpose of PACKED words (lane=unit -> fragment)
      hT[wv][0][l] = (unsigned)r0;
      hT[wv][1][l] = (unsigned)r1;
      hT[wv][2][l] = (unsigned)r2;
      hT[wv][3][l] = (unsigned)r3;
      hT[wv][4][l] = (unsigned)r4;
      hT[wv][5][l] = (unsigned)r5;
      hT[wv][6][l] = (unsigned)r6;
      hT[wv][7][l] = (unsigned)r7;

      // B fragments: batch cols 0-7 (cols 8-15 garbage -> discarded D cols)
      short8v Bhi[2], Blo[2];
#pragma unroll
      for (int ks = 0; ks < 2; ++ks) {
        unsigned hw[4], lw[4];
#pragma unroll
        for (int p = 0; p < 4; ++p) {
          unsigned u0 = 0, u1 = 0;
          if (bact) {
            const uint2 v = *(const uint2*)&hT[wv][col][32 * ks + 8 * kg + 2 * p];
            u0 = v.x; u1 = v.y;
          }
          hw[p] = (u1 & 0xffff0000u) | (u0 >> 16);     // hi(k1)|hi(k0)
          lw[p] = (u1 << 16) | (u0 & 0xffffu);         // lo(k1)|lo(k0)
        }
        uint4v ph = {hw[0], hw[1], hw[2], hw[3]};
        uint4v pl = {lw[0], lw[1], lw[2], lw[3]};
        Bhi[ks] = __builtin_bit_cast(short8v, ph);
        Blo[ks] = __builtin_bit_cast(short8v, pl);
      }
      // 3-term split-bf16 MFMA (layouts validated r17-r19): 24 total
#pragma unroll
      for (int j = 0; j < 4; ++j) {
#pragma unroll
        for (int ks = 0; ks < 2; ++ks) {
          acc[j] = __builtin_amdgcn_mfma_f32_16x16x32_bf16(Ahi[j][ks], Bhi[ks], acc[j], 0, 0, 0);
          acc[j] = __builtin_amdgcn_mfma_f32_16x16x32_bf16(Alo[j][ks], Bhi[ks], acc[j], 0, 0, 0);
          acc[j] = __builtin_amdgcn_mfma_f32_16x16x32_bf16(Ahi[j][ks], Blo[ks], acc[j], 0, 0, 0);
        }
      }
    }

    // publish k-partials (also zeros at s=0): D col=l&15 (batch), row=kg*4+r
    if (bact) {
#pragma unroll
      for (int j = 0; j < 4; ++j)
#pragma unroll
        for (int r = 0; r < 4; ++r)
          red[par][wv][j][kg * 4 + r][col] = acc[j][r];
    }
    __syncthreads();     // the ONE barrier per step

    // gates: tid<128, one (unit gu, batch gb) pair each
    if (tid < 128) {
      float z0 = xv0, z1 = xv1, z2 = xv2, z3 = xv3;
#pragma unroll
      for (int w2 = 0; w2 < 8; ++w2) {
        z0 += red[par][w2][0][gu][gb];
        z1 += red[par][w2][1][gu][gb];
        z2 += red[par][w2][2][gu][gb];
        z3 += red[par][w2][3][gu][gb];
      }
      float i_ = 1.f / (1.f + expf(-z0));
      float f_ = 1.f / (1.f + expf(-z1));
      float g_ = tanhf(z2);
      float o_ = 1.f / (1.f + expf(-z3));
      c_state = f_ * c_state + i_ * g_;
      float h_ = o_ * tanhf(c_state);
      // packed tagged message: tag32 | (hi16<<16 | lo16)
      unsigned uh = __float_as_uint(h_);
      unsigned hi16 = uh >> 16;
      float rem = h_ - __uint_as_float(uh & 0xffff0000u);
      unsigned lo16 = __float_as_uint(rem) >> 16;
      ull pv = ((ull)(unsigned)(s + 1) << 32) | (ull)((hi16 << 16) | lo16);
      __hip_atomic_store(
          &h_buf[(((size_t)par2 * TEAMS + team) * TB + gb) * HDIM + unit],
          pv, __ATOMIC_RELAXED, __HIP_MEMORY_SCOPE_AGENT);
      states[((size_t)s * BATCH + team * TB + gb) * HDIM + unit] = h_;
    }
    // no trailing barrier: red(s+1) goes to par^1; red(par) reuse at s+2 is
    // ordered by tag-wait(s+1) => all team WGs passed barrier(s) => gates(s)
    // reads done (r9/r16 transitive argument; all-to-all team consumption).
  }
}

// ---------------- attention GEMM (unchanged r16) ----------------
#define ATP 132
__global__ __launch_bounds__(256) void attn_gemm(
    const float* __restrict__ states, const float* __restrict__ W_word,
    const float* __restrict__ b_word, const float* __restrict__ w_proj,
    float* __restrict__ part) {
  __shared__ float At[16][ATP];
  __shared__ float Bt[16][ATP];
  __shared__ float redl[128][17];

  const int tid = threadIdx.x;
  const int m0 = blockIdx.x * 128;
  const int n0 = blockIdx.y * 128;
  const int ty = tid >> 4, tx = tid & 15;

  float acc[8][8];
#pragma unroll
  for (int i = 0; i < 8; ++i)
#pragma unroll
    for (int j = 0; j < 8; ++j) acc[i][j] = 0.f;

  for (int k0 = 0; k0 < 512; k0 += 16) {
#pragma unroll
    for (int it = 0; it < 2; ++it) {
      int m = (tid >> 2) + 64 * it;
      int kq = tid & 3;
      float4 v = *(const float4*)&states[(size_t)(m0 + m) * 512 + k0 + 4 * kq];
      At[4 * kq + 0][m] = v.x; At[4 * kq + 1][m] = v.y;
      At[4 * kq + 2][m] = v.z; At[4 * kq + 3][m] = v.w;
    }
#pragma unroll
    for (int it = 0; it < 2; ++it) {
      int kr = (tid >> 5) + 8 * it;
      int nq = tid & 31;
      float4 v = *(const float4*)&W_word[(size_t)(k0 + kr) * 512 + n0 + 4 * nq];
      *(float4*)&Bt[kr][4 * nq] = v;
    }
    __syncthreads();
#pragma unroll
    for (int kk = 0; kk < 16; ++kk) {
      float4 a0 = *(const float4*)&At[kk][ty * 8];
      float4 a1 = *(const float4*)&At[kk][ty * 8 + 4];
      float4 b0 = *(const float4*)&Bt[kk][tx * 8];
      float4 b1 = *(const float4*)&Bt[kk][tx * 8 + 4];
      float av[8] = {a0.x, a0.y, a0.z, a0.w, a1.x, a1.y, a1.z, a1.w};
      float bv[8] = {b0.x, b0.y, b0.z, b0.w, b1.x, b1.y, b1.z, b1.w};
#pragma unroll
      for (int i = 0; i < 8; ++i)
#pragma unroll
        for (int j = 0; j < 8; ++j) acc[i][j] = fmaf(av[i], bv[j], acc[i][j]);
    }
    __syncthreads();
  }
  float bw[8], wp[8];
  {
    float4 v0 = *(const float4*)&b_word[n0 + tx * 8];
    float4 v1 = *(const float4*)&b_word[n0 + tx * 8 + 4];
    bw[0]=v0.x; bw[1]=v0.y; bw[2]=v0.z; bw[3]=v0.w; bw[4]=v1.x; bw[5]=v1.y; bw[6]=v1.z; bw[7]=v1.w;
    float4 u0 = *(const float4*)&w_proj[n0 + tx * 8];
    float4 u1 = *(const float4*)&w_proj[n0 + tx * 8 + 4];
    wp[0]=u0.x; wp[1]=u0.y; wp[2]=u0.z; wp[3]=u0.w; wp[4]=u1.x; wp[5]=u1.y; wp[6]=u1.z; wp[7]=u1.w;
  }
#pragma unroll
  for (int i = 0; i < 8; ++i) {
    float rs = 0.f;
#pragma unroll
    for (int j = 0; j < 8; ++j) rs += tanhf(acc[i][j] + bw[j]) * wp[j];
    redl[ty * 8 + i][tx] = rs;
  }
  __syncthreads();
  if (tid < 128) {
    float ssum = 0.f;
#pragma unroll
    for (int x = 0; x < 16; ++x) ssum += redl[tid][x];
    part[(size_t)blockIdx.y * (S_LEN * BATCH) + m0 + tid] = ssum;
  }
}

// ---------------- phase A: per-(batch, S-slice) online-softmax partials ----------------
__global__ __launch_bounds__(256) void pool_partial(
    const float* __restrict__ part, const float* __restrict__ states,
    float* __restrict__ poolP, float* __restrict__ ml) {
  const int b = blockIdx.x >> 3;
  const int sl = blockIdx.x & 7;
  const int s0 = sl * SLICE_LEN;
  const int len = (sl == 7) ? (S_LEN - 7 * SLICE_LEN) : SLICE_LEN;
  const int tid = threadIdx.x;

  __shared__ float es[SLICE_LEN];
  __shared__ float redm[256];

  float sc = -1e30f;
  if (tid < len) {
    const int t = (s0 + tid) * BATCH + b;
    sc = part[t] + part[S_LEN * BATCH + t] + part[2 * S_LEN * BATCH + t] +
         part[3 * S_LEN * BATCH + t];
  }
  redm[tid] = sc;
  __syncthreads();
  for (int o = 128; o > 0; o >>= 1) {
    if (tid < o) redm[tid] = fmaxf(redm[tid], redm[tid + o]);
    __syncthreads();
  }
  const float m_sl = redm[0];
  __syncthreads();
  float e = 0.f;
  if (tid < len) e = expf(sc - m_sl);
  if (tid < SLICE_LEN) es[tid] = (tid < len) ? e : 0.f;
  redm[tid] = e;
  __syncthreads();
  for (int o = 128; o > 0; o >>= 1) {
    if (tid < o) redm[tid] += redm[tid + o];
    __syncthreads();
  }
  if (tid == 0) {
    ml[(b * NSLICE + sl) * 2 + 0] = m_sl;
    ml[(b * NSLICE + sl) * 2 + 1] = redm[0];
  }
  __syncthreads();

  for (int h = tid; h < HDIM; h += 256) {
    float a = 0.f;
    for (int s = 0; s < len; ++s)
      a = fmaf(es[s], states[((size_t)(s0 + s) * BATCH + b) * HDIM + h], a);
    poolP[((size_t)b * NSLICE + sl) * HDIM + h] = a;
  }
}

// ---------------- phase B: merge slices + decode ----------------
__global__ __launch_bounds__(256) void pool_merge_decode(
    const float* __restrict__ poolP, const float* __restrict__ ml,
    const float* __restrict__ dec_W, const float* __restrict__ dec_b,
    float* __restrict__ out) {
  const int b = blockIdx.x;
  const int tid = threadIdx.x;
  __shared__ float pool[HDIM];
  __shared__ float redm[256];
  __shared__ float wsl[NSLICE];

  if (tid == 0) {
    float gmax = -1e30f;
#pragma unroll
    for (int i = 0; i < NSLICE; ++i) gmax = fmaxf(gmax, ml[(b * NSLICE + i) * 2]);
    float Z = 0.f;
#pragma unroll
    for (int i = 0; i < NSLICE; ++i) {
      float w = expf(ml[(b * NSLICE + i) * 2] - gmax);
      wsl[i] = w;
      Z = fmaf(ml[(b * NSLICE + i) * 2 + 1], w, Z);
    }
    redm[0] = 1.f / Z;
  }
  __syncthreads();
  const float inv = redm[0];

  for (int h = tid; h < HDIM; h += 256) {
    float a = 0.f;
#pragma unroll
    for (int i = 0; i < NSLICE; ++i)
      a = fmaf(wsl[i], poolP[((size_t)b * NSLICE + i) * HDIM + h], a);
    pool[h] = a * inv;
  }
  __syncthreads();
  const int lcls = tid >> 7, ch = tid & 127;
  float p = 0.f;
#pragma unroll
  for (int j = 0; j < 4; ++j)
    p = fmaf(pool[ch * 4 + j], dec_W[lcls * HDIM + ch * 4 + j], p);
  redm[tid] = p;
  __syncthreads();
  for (int o = 64; o > 0; o >>= 1) {
    if (ch < o) redm[tid] += redm[tid + o];
    __syncthreads();
  }
  if (ch == 0) out[b * 2 + lcls] = redm[tid] + dec_b[lcls];
}

extern "C" void kernel_launch(void* const* d_in, const int* in_sizes, int n_in,
                              void* d_out, int out_size, void* d_ws, size_t ws_size,
                              hipStream_t stream) {
  const int*   idx    = (const int*)d_in[0];
  // d_in[1] = text_lengths: unused by the reference
  const float* emb    = (const float*)d_in[2];
  const float* W_ih   = (const float*)d_in[3];
  const float* W_hh   = (const float*)d_in[4];
  const float* b_ih   = (const float*)d_in[5];
  const float* b_hh   = (const float*)d_in[6];
  const float* W_word = (const float*)d_in[7];
  const float* b_word = (const float*)d_in[8];
  const float* w_proj = (const float*)d_in[9];
  const float* dec_W  = (const float*)d_in[10];
  const float* dec_b  = (const float*)d_in[11];
  float* out = (float*)d_out;

  char* ws = (char*)d_ws;
  float* xproj  = (float*)ws;
  float* states = (float*)(ws + STATES_OFF);
  ull*   h_buf  = (ull*)(ws + HBUF_OFF);
  float* part   = (float*)(ws + PART_OFF);
  float* poolP  = (float*)(ws + POOLP_OFF);
  float* ml     = (float*)(ws + ML_OFF);

  // tags must start invalid each launch (prevents cross-replay tag collision)
  hipMemsetAsync(h_buf, 0, HBUF_BYTES, stream);

  // 1) x-projection for all timesteps (parallel GEMM, 67 GFLOP)
  xproj_gemm<<<dim3(250, 16), 256, 0, stream>>>(idx, emb, W_ih, b_ih, b_hh, xproj);

  // 2) recurrence (persistent cooperative, proven 256-block shape)
  void* args[] = {(void*)&xproj, (void*)&W_hh, (void*)&states, (void*)&h_buf};
  hipLaunchCooperativeKernel(lstm_persistent, dim3(NBLOCKS), dim3(NTHREADS), args, 0, stream);

  // 3) attention scores + 4) two-phase softmax/pool + decode
  attn_gemm<<<dim3(250, 4), 256, 0, stream>>>(states, W_word, b_word, w_proj, part);
  pool_partial<<<BATCH * NSLICE, 256, 0, stream>>>(part, states, poolP, ml);
  pool_merge_decode<<<BATCH, 256, 0, stream>>>(poolP, ml, dec_W, dec_b, out);
}

// Round 21
// 2809.712 us; speedup vs baseline: 1.0677x; 1.0677x over previous
//
#include <hip/hip_runtime.h>

// SentimentNet on MI355X — round 21: FINAL — revert to r19 (measured best,
// 2838us total; r20's single-phase regressed: LDS bank conflicts 4x from
// the widened hT/red layouts + full-8-batch detect tail).
//
// Final structure: xproj GEMM (250x16 blocks) -> persistent cooperative
// recurrence (256 blocks, two 4-batch phases/step, split-bf16 MFMA dot,
// packed tagged LLC h-exchange, fenceless relaxed atomics) -> attn GEMM ->
// two-phase parallel softmax-pool -> decode.

#define S_LEN 500
#define BATCH 64
#define EDIM 512
#define HDIM 512
#define TEAMS 8
#define WGS_PER_TEAM 32
#define TB 8
#define NBLOCKS (TEAMS * WGS_PER_TEAM)
#define NTHREADS 512
#define NSLICE 8
#define SLICE_LEN 63              // 7*63 + 59 = 500

typedef unsigned long long ull;
typedef __attribute__((ext_vector_type(8))) short short8v;
typedef __attribute__((ext_vector_type(4))) float float4v;
typedef __attribute__((ext_vector_type(4))) unsigned int uint4v;

// workspace layout (bytes)
#define XPROJ_BYTES  ((size_t)S_LEN * 2048 * BATCH * 4)   // 262,144,000
#define STATES_OFF   XPROJ_BYTES
#define STATES_BYTES ((size_t)S_LEN * BATCH * HDIM * 4)   // 65,536,000
#define HBUF_OFF     (STATES_OFF + STATES_BYTES)
#define HBUF_BYTES   ((size_t)2 * TEAMS * TB * HDIM * 8)  // 524,288 (ull)
#define PART_OFF     (HBUF_OFF + HBUF_BYTES)
#define PART_BYTES   (4 * S_LEN * BATCH * 4)              // 512,000
#define POOLP_OFF    (PART_OFF + PART_BYTES)
#define POOLP_BYTES  ((size_t)BATCH * NSLICE * HDIM * 4)  // 1,048,576
#define ML_OFF       (POOLP_OFF + POOLP_BYTES)
#define ML_BYTES     (BATCH * NSLICE * 2 * 4)             // 4,096

// ---------------- xproj GEMM ----------------
__global__ __launch_bounds__(256) void xproj_gemm(
    const int* __restrict__ idx, const float* __restrict__ emb,
    const float* __restrict__ W_ih, const float* __restrict__ b_ih,
    const float* __restrict__ b_hh, float* __restrict__ xproj) {
  __shared__ float At[16][132];   // [k][g]
  __shared__ float Bt[16][132];   // [k][sb]
  __shared__ int sidx[128];

  const int tid = threadIdx.x;
  const int sb0 = blockIdx.x * 128;
  const int g0  = blockIdx.y * 128;
  if (tid < 128) sidx[tid] = idx[sb0 + tid];

  const int ty = tid >> 4, tx = tid & 15;
  const int ra = tid & 127, pp = tid >> 7;

  float acc[8][8];
#pragma unroll
  for (int i = 0; i < 8; ++i)
#pragma unroll
    for (int j = 0; j < 8; ++j) acc[i][j] = 0.f;

  __syncthreads();

  for (int k0 = 0; k0 < 512; k0 += 16) {
    const float* pa = &W_ih[(size_t)(g0 + ra) * 512 + k0 + 8 * pp];
    float4 a0 = *(const float4*)pa, a1 = *(const float4*)(pa + 4);
    const float* pb = &emb[(size_t)sidx[ra] * 512 + k0 + 8 * pp];
    float4 b0 = *(const float4*)pb, b1 = *(const float4*)(pb + 4);
    At[8*pp+0][ra]=a0.x; At[8*pp+1][ra]=a0.y; At[8*pp+2][ra]=a0.z; At[8*pp+3][ra]=a0.w;
    At[8*pp+4][ra]=a1.x; At[8*pp+5][ra]=a1.y; At[8*pp+6][ra]=a1.z; At[8*pp+7][ra]=a1.w;
    Bt[8*pp+0][ra]=b0.x; Bt[8*pp+1][ra]=b0.y; Bt[8*pp+2][ra]=b0.z; Bt[8*pp+3][ra]=b0.w;
    Bt[8*pp+4][ra]=b1.x; Bt[8*pp+5][ra]=b1.y; Bt[8*pp+6][ra]=b1.z; Bt[8*pp+7][ra]=b1.w;
    __syncthreads();
#pragma unroll
    for (int kk = 0; kk < 16; ++kk) {
      float4 x0 = *(const float4*)&At[kk][ty * 8];
      float4 x1 = *(const float4*)&At[kk][ty * 8 + 4];
      float4 y0 = *(const float4*)&Bt[kk][tx * 8];
      float4 y1 = *(const float4*)&Bt[kk][tx * 8 + 4];
      float av[8] = {x0.x, x0.y, x0.z, x0.w, x1.x, x1.y, x1.z, x1.w};
      float bv[8] = {y0.x, y0.y, y0.z, y0.w, y1.x, y1.y, y1.z, y1.w};
#pragma unroll
      for (int i = 0; i < 8; ++i)
#pragma unroll
        for (int j = 0; j < 8; ++j) acc[i][j] = fmaf(av[i], bv[j], acc[i][j]);
    }
    __syncthreads();
  }
  const int sbb = sb0 + tx * 8;
  const int s  = sbb >> 6;
  const int tm = (sbb & 63) >> 3;
#pragma unroll
  for (int i = 0; i < 8; ++i) {
    const int g = g0 + ty * 8 + i;
    const float bias = b_ih[g] + b_hh[g];
    float* dst = &xproj[(((size_t)s * TEAMS + tm) * 2048 + g) * 8];
    float4 v0 = {acc[i][0] + bias, acc[i][1] + bias, acc[i][2] + bias, acc[i][3] + bias};
    float4 v1 = {acc[i][4] + bias, acc[i][5] + bias, acc[i][6] + bias, acc[i][7] + bias};
    *(float4*)dst = v0;
    *(float4*)(dst + 4) = v1;
  }
}

// ---------------- persistent recurrence (two-phase MFMA, r19) ----------------
__global__ __launch_bounds__(NTHREADS, 1) void lstm_persistent(
    const float* __restrict__ xproj, const float* __restrict__ W_hh,
    float* __restrict__ states, ull* __restrict__ h_buf) {
  __shared__ float red[2][8][4][16][5];   // [G][wave][j][u][b] (pad 5) = 20KB
  __shared__ unsigned hT[8][4][66];       // wave-private transpose buf (packed)

  const int team = blockIdx.x & 7;           // XCD-local teams
  const int wg   = blockIdx.x >> 3;          // 0..31 -> units [16wg, 16wg+16)
  const int tid  = threadIdx.x;
  const int wv   = tid >> 6;                 // wave 0..7 -> k chunk [64wv, 64wv+64)
  const int l    = tid & 63;                 // lane

  const int col = l & 15;                    // MFMA A-row / B-col / D-col
  const int kg  = l >> 4;                    // k-group 0..3

  // ---- A fragments: W_hh split hi/lo bf16, fragment order, reg-stationary
  short8v Ahi[4][2], Alo[4][2];
#pragma unroll
  for (int j = 0; j < 4; ++j)
#pragma unroll
    for (int ks = 0; ks < 2; ++ks) {
      const float* wr = &W_hh[((size_t)(16 * wg + col) + 512 * j) * 512
                              + 64 * wv + 32 * ks + 8 * kg];
      unsigned hw[4], lw[4];
#pragma unroll
      for (int p = 0; p < 4; ++p) {
        float w0 = wr[2 * p], w1 = wr[2 * p + 1];
        unsigned u0 = __float_as_uint(w0), u1 = __float_as_uint(w1);
        hw[p] = (u1 & 0xffff0000u) | (u0 >> 16);
        float l0 = w0 - __uint_as_float(u0 & 0xffff0000u);
        float l1 = w1 - __uint_as_float(u1 & 0xffff0000u);
        lw[p] = (__float_as_uint(l1) & 0xffff0000u) | (__float_as_uint(l0) >> 16);
      }
      uint4v ph = {hw[0], hw[1], hw[2], hw[3]};
      uint4v pl = {lw[0], lw[1], lw[2], lw[3]};
      Ahi[j][ks] = __builtin_bit_cast(short8v, ph);
      Alo[j][ks] = __builtin_bit_cast(short8v, pl);
    }

  // gate identity (wave G acts): unit gu, local batch gbl (0..3)
  const int gu = l & 15, gbl = l >> 4;
  const int unit = 16 * wg + gu;
  float c_state = 0.f;
  const float* xpbase = xproj + (size_t)(16 * wg + gu) * 8 + (wv * 4 + gbl);

  const bool bact = (col < 4);               // B-active lane (batch col)

  for (int s = 0; s < S_LEN; ++s) {
    const int par = s & 1, par2 = (s + 1) & 1;

    // step-top prefetch: all 8 batches' tagged h loads, coalesced (lane=unit)
    ull pre0 = 0, pre1 = 0, pre2 = 0, pre3 = 0;
    ull pre4 = 0, pre5 = 0, pre6 = 0, pre7 = 0;
    const ull* hb0 = h_buf + (((size_t)par * TEAMS + team) * TB) * HDIM
                     + (size_t)64 * wv + l;
    if (s > 0) {
      pre0 = __hip_atomic_load(hb0 + 0 * HDIM, __ATOMIC_RELAXED, __HIP_MEMORY_SCOPE_AGENT);
      pre1 = __hip_atomic_load(hb0 + 1 * HDIM, __ATOMIC_RELAXED, __HIP_MEMORY_SCOPE_AGENT);
      pre2 = __hip_atomic_load(hb0 + 2 * HDIM, __ATOMIC_RELAXED, __HIP_MEMORY_SCOPE_AGENT);
      pre3 = __hip_atomic_load(hb0 + 3 * HDIM, __ATOMIC_RELAXED, __HIP_MEMORY_SCOPE_AGENT);
      pre4 = __hip_atomic_load(hb0 + 4 * HDIM, __ATOMIC_RELAXED, __HIP_MEMORY_SCOPE_AGENT);
      pre5 = __hip_atomic_load(hb0 + 5 * HDIM, __ATOMIC_RELAXED, __HIP_MEMORY_SCOPE_AGENT);
      pre6 = __hip_atomic_load(hb0 + 6 * HDIM, __ATOMIC_RELAXED, __HIP_MEMORY_SCOPE_AGENT);
      pre7 = __hip_atomic_load(hb0 + 7 * HDIM, __ATOMIC_RELAXED, __HIP_MEMORY_SCOPE_AGENT);
    }

#pragma unroll
    for (int G = 0; G < 2; ++G) {
      // gate wave for G prefetches its 4 xproj values (consumed after sync)
      float xv0, xv1, xv2, xv3;
      if (wv == G) {
        const float* p = xpbase + ((size_t)s * TEAMS + team) * (2048 * 8);
        xv0 = p[0]; xv1 = p[512 * 8]; xv2 = p[1024 * 8]; xv3 = p[1536 * 8];
      }

      float4v acc[4];
#pragma unroll
      for (int j = 0; j < 4; ++j) acc[j] = (float4v){0.f, 0.f, 0.f, 0.f};

      if (s > 0) {
        // use prefetched words; coalesced retry fallback on stale tags
        ull r0 = (G == 0) ? pre0 : pre4;
        ull r1 = (G == 0) ? pre1 : pre5;
        ull r2 = (G == 0) ? pre2 : pre6;
        ull r3 = (G == 0) ? pre3 : pre7;
        bool ok = ((int)(r0 >> 32) == s) & ((int)(r1 >> 32) == s) &
                  ((int)(r2 >> 32) == s) & ((int)(r3 >> 32) == s);
        if (!__all(ok)) {
          const ull* hb = hb0 + (size_t)(G * 4) * HDIM;
          int spins = 0;
          for (;;) {
            r0 = __hip_atomic_load(hb + 0 * HDIM, __ATOMIC_RELAXED, __HIP_MEMORY_SCOPE_AGENT);
            r1 = __hip_atomic_load(hb + 1 * HDIM, __ATOMIC_RELAXED, __HIP_MEMORY_SCOPE_AGENT);
            r2 = __hip_atomic_load(hb + 2 * HDIM, __ATOMIC_RELAXED, __HIP_MEMORY_SCOPE_AGENT);
            r3 = __hip_atomic_load(hb + 3 * HDIM, __ATOMIC_RELAXED, __HIP_MEMORY_SCOPE_AGENT);
            ok = ((int)(r0 >> 32) == s) & ((int)(r1 >> 32) == s) &
                 ((int)(r2 >> 32) == s) & ((int)(r3 >> 32) == s);
            if (__all(ok)) break;
            __builtin_amdgcn_s_sleep(1);
            if (++spins > (1 << 18)) break;    // hang guard only
          }
        }
        // intra-wave LDS transpose of PACKED words (lane=unit -> fragment)
        hT[wv][0][l] = (unsigned)r0;
        hT[wv][1][l] = (unsigned)r1;
        hT[wv][2][l] = (unsigned)r2;
        hT[wv][3][l] = (unsigned)r3;

        // build B fragments with pure bit-ops (producer pre-split hi|lo)
        short8v Bhi[2], Blo[2];
#pragma unroll
        for (int ks = 0; ks < 2; ++ks) {
          unsigned hw[4], lw[4];
#pragma unroll
          for (int p = 0; p < 4; ++p) {
            unsigned u0 = 0, u1 = 0;
            if (bact) {
              const uint2 v = *(const uint2*)&hT[wv][col][32 * ks + 8 * kg + 2 * p];
              u0 = v.x; u1 = v.y;
            }
            hw[p] = (u1 & 0xffff0000u) | (u0 >> 16);     // hi(k1)|hi(k0)
            lw[p] = (u1 << 16) | (u0 & 0xffffu);         // lo(k1)|lo(k0)
          }
          uint4v ph = {hw[0], hw[1], hw[2], hw[3]};
          uint4v pl = {lw[0], lw[1], lw[2], lw[3]};
          Bhi[ks] = __builtin_bit_cast(short8v, ph);
          Blo[ks] = __builtin_bit_cast(short8v, pl);
        }
        // 3-term split-bf16 MFMA (layouts validated r17/r18)
#pragma unroll
        for (int j = 0; j < 4; ++j) {
#pragma unroll
          for (int ks = 0; ks < 2; ++ks) {
            acc[j] = __builtin_amdgcn_mfma_f32_16x16x32_bf16(Ahi[j][ks], Bhi[ks], acc[j], 0, 0, 0);
            acc[j] = __builtin_amdgcn_mfma_f32_16x16x32_bf16(Alo[j][ks], Bhi[ks], acc[j], 0, 0, 0);
            acc[j] = __builtin_amdgcn_mfma_f32_16x16x32_bf16(Ahi[j][ks], Blo[ks], acc[j], 0, 0, 0);
          }
        }
      }

      // publish k-partials: D lane mapping col=l&15 (batch), row=(l>>4)*4+r
      if (bact) {
#pragma unroll
        for (int j = 0; j < 4; ++j)
#pragma unroll
          for (int r = 0; r < 4; ++r)
            red[G][wv][j][kg * 4 + r][col] = acc[j][r];
      }
      __syncthreads();

      // fused reduce + gates + exchange store: gate wave G only
      if (wv == G) {
        float z0 = xv0, z1 = xv1, z2 = xv2, z3 = xv3;
#pragma unroll
        for (int w2 = 0; w2 < 8; ++w2) {
          z0 += red[G][w2][0][gu][gbl];
          z1 += red[G][w2][1][gu][gbl];
          z2 += red[G][w2][2][gu][gbl];
          z3 += red[G][w2][3][gu][gbl];
        }
        float i_ = 1.f / (1.f + expf(-z0));
        float f_ = 1.f / (1.f + expf(-z1));
        float g_ = tanhf(z2);
        float o_ = 1.f / (1.f + expf(-z3));
        c_state = f_ * c_state + i_ * g_;
        float h_ = o_ * tanhf(c_state);
        // pack hi/lo bf16 ONCE at the producer: data = hi16<<16 | lo16
        unsigned uh = __float_as_uint(h_);
        unsigned hi16 = uh >> 16;
        float rem = h_ - __uint_as_float(uh & 0xffff0000u);
        unsigned lo16 = __float_as_uint(rem) >> 16;
        ull pv = ((ull)(unsigned)(s + 1) << 32) | (ull)((hi16 << 16) | lo16);
        __hip_atomic_store(
            &h_buf[(((size_t)par2 * TEAMS + team) * TB + G * 4 + gbl) * HDIM + unit],
            pv, __ATOMIC_RELAXED, __HIP_MEMORY_SCOPE_AGENT);
        states[((size_t)s * BATCH + team * TB + G * 4 + gbl) * HDIM + unit] = h_;
      }
      // no trailing barrier: red[G] reuse at s+2 ordered by tag-wait(s+1)
      // (r8 transitive argument); hT is wave-private.
    }
  }
}

// ---------------- attention GEMM ----------------
#define ATP 132
__global__ __launch_bounds__(256) void attn_gemm(
    const float* __restrict__ states, const float* __restrict__ W_word,
    const float* __restrict__ b_word, const float* __restrict__ w_proj,
    float* __restrict__ part) {
  __shared__ float At[16][ATP];
  __shared__ float Bt[16][ATP];
  __shared__ float redl[128][17];

  const int tid = threadIdx.x;
  const int m0 = blockIdx.x * 128;
  const int n0 = blockIdx.y * 128;
  const int ty = tid >> 4, tx = tid & 15;

  float acc[8][8];
#pragma unroll
  for (int i = 0; i < 8; ++i)
#pragma unroll
    for (int j = 0; j < 8; ++j) acc[i][j] = 0.f;

  for (int k0 = 0; k0 < 512; k0 += 16) {
#pragma unroll
    for (int it = 0; it < 2; ++it) {
      int m = (tid >> 2) + 64 * it;
      int kq = tid & 3;
      float4 v = *(const float4*)&states[(size_t)(m0 + m) * 512 + k0 + 4 * kq];
      At[4 * kq + 0][m] = v.x; At[4 * kq + 1][m] = v.y;
      At[4 * kq + 2][m] = v.z; At[4 * kq + 3][m] = v.w;
    }
#pragma unroll
    for (int it = 0; it < 2; ++it) {
      int kr = (tid >> 5) + 8 * it;
      int nq = tid & 31;
      float4 v = *(const float4*)&W_word[(size_t)(k0 + kr) * 512 + n0 + 4 * nq];
      *(float4*)&Bt[kr][4 * nq] = v;
    }
    __syncthreads();
#pragma unroll
    for (int kk = 0; kk < 16; ++kk) {
      float4 a0 = *(const float4*)&At[kk][ty * 8];
      float4 a1 = *(const float4*)&At[kk][ty * 8 + 4];
      float4 b0 = *(const float4*)&Bt[kk][tx * 8];
      float4 b1 = *(const float4*)&Bt[kk][tx * 8 + 4];
      float av[8] = {a0.x, a0.y, a0.z, a0.w, a1.x, a1.y, a1.z, a1.w};
      float bv[8] = {b0.x, b0.y, b0.z, b0.w, b1.x, b1.y, b1.z, b1.w};
#pragma unroll
      for (int i = 0; i < 8; ++i)
#pragma unroll
        for (int j = 0; j < 8; ++j) acc[i][j] = fmaf(av[i], bv[j], acc[i][j]);
    }
    __syncthreads();
  }
  float bw[8], wp[8];
  {
    float4 v0 = *(const float4*)&b_word[n0 + tx * 8];
    float4 v1 = *(const float4*)&b_word[n0 + tx * 8 + 4];
    bw[0]=v0.x; bw[1]=v0.y; bw[2]=v0.z; bw[3]=v0.w; bw[4]=v1.x; bw[5]=v1.y; bw[6]=v1.z; bw[7]=v1.w;
    float4 u0 = *(const float4*)&w_proj[n0 + tx * 8];
    float4 u1 = *(const float4*)&w_proj[n0 + tx * 8 + 4];
    wp[0]=u0.x; wp[1]=u0.y; wp[2]=u0.z; wp[3]=u0.w; wp[4]=u1.x; wp[5]=u1.y; wp[6]=u1.z; wp[7]=u1.w;
  }
#pragma unroll
  for (int i = 0; i < 8; ++i) {
    float rs = 0.f;
#pragma unroll
    for (int j = 0; j < 8; ++j) rs += tanhf(acc[i][j] + bw[j]) * wp[j];
    redl[ty * 8 + i][tx] = rs;
  }
  __syncthreads();
  if (tid < 128) {
    float ssum = 0.f;
#pragma unroll
    for (int x = 0; x < 16; ++x) ssum += redl[tid][x];
    part[(size_t)blockIdx.y * (S_LEN * BATCH) + m0 + tid] = ssum;
  }
}

// ---------------- phase A: per-(batch, S-slice) online-softmax partials ----------------
__global__ __launch_bounds__(256) void pool_partial(
    const float* __restrict__ part, const float* __restrict__ states,
    float* __restrict__ poolP, float* __restrict__ ml) {
  const int b = blockIdx.x >> 3;
  const int sl = blockIdx.x & 7;
  const int s0 = sl * SLICE_LEN;
  const int len = (sl == 7) ? (S_LEN - 7 * SLICE_LEN) : SLICE_LEN;
  const int tid = threadIdx.x;

  __shared__ float es[SLICE_LEN];
  __shared__ float redm[256];

  float sc = -1e30f;
  if (tid < len) {
    const int t = (s0 + tid) * BATCH + b;
    sc = part[t] + part[S_LEN * BATCH + t] + part[2 * S_LEN * BATCH + t] +
         part[3 * S_LEN * BATCH + t];
  }
  redm[tid] = sc;
  __syncthreads();
  for (int o = 128; o > 0; o >>= 1) {
    if (tid < o) redm[tid] = fmaxf(redm[tid], redm[tid + o]);
    __syncthreads();
  }
  const float m_sl = redm[0];
  __syncthreads();
  float e = 0.f;
  if (tid < len) e = expf(sc - m_sl);
  if (tid < SLICE_LEN) es[tid] = (tid < len) ? e : 0.f;
  redm[tid] = e;
  __syncthreads();
  for (int o = 128; o > 0; o >>= 1) {
    if (tid < o) redm[tid] += redm[tid + o];
    __syncthreads();
  }
  if (tid == 0) {
    ml[(b * NSLICE + sl) * 2 + 0] = m_sl;
    ml[(b * NSLICE + sl) * 2 + 1] = redm[0];
  }
  __syncthreads();

  for (int h = tid; h < HDIM; h += 256) {
    float a = 0.f;
    for (int s = 0; s < len; ++s)
      a = fmaf(es[s], states[((size_t)(s0 + s) * BATCH + b) * HDIM + h], a);
    poolP[((size_t)b * NSLICE + sl) * HDIM + h] = a;
  }
}

// ---------------- phase B: merge slices + decode ----------------
__global__ __launch_bounds__(256) void pool_merge_decode(
    const float* __restrict__ poolP, const float* __restrict__ ml,
    const float* __restrict__ dec_W, const float* __restrict__ dec_b,
    float* __restrict__ out) {
  const int b = blockIdx.x;
  const int tid = threadIdx.x;
  __shared__ float pool[HDIM];
  __shared__ float redm[256];
  __shared__ float wsl[NSLICE];

  if (tid == 0) {
    float gmax = -1e30f;
#pragma unroll
    for (int i = 0; i < NSLICE; ++i) gmax = fmaxf(gmax, ml[(b * NSLICE + i) * 2]);
    float Z = 0.f;
#pragma unroll
    for (int i = 0; i < NSLICE; ++i) {
      float w = expf(ml[(b * NSLICE + i) * 2] - gmax);
      wsl[i] = w;
      Z = fmaf(ml[(b * NSLICE + i) * 2 + 1], w, Z);
    }
    redm[0] = 1.f / Z;
  }
  __syncthreads();
  const float inv = redm[0];

  for (int h = tid; h < HDIM; h += 256) {
    float a = 0.f;
#pragma unroll
    for (int i = 0; i < NSLICE; ++i)
      a = fmaf(wsl[i], poolP[((size_t)b * NSLICE + i) * HDIM + h], a);
    pool[h] = a * inv;
  }
  __syncthreads();
  const int lcls = tid >> 7, ch = tid & 127;
  float p = 0.f;
#pragma unroll
  for (int j = 0; j < 4; ++j)
    p = fmaf(pool[ch * 4 + j], dec_W[lcls * HDIM + ch * 4 + j], p);
  redm[tid] = p;
  __syncthreads();
  for (int o = 64; o > 0; o >>= 1) {
    if (ch < o) redm[tid] += redm[tid + o];
    __syncthreads();
  }
  if (ch == 0) out[b * 2 + lcls] = redm[tid] + dec_b[lcls];
}

extern "C" void kernel_launch(void* const* d_in, const int* in_sizes, int n_in,
                              void* d_out, int out_size, void* d_ws, size_t ws_size,
                              hipStream_t stream) {
  const int*   idx    = (const int*)d_in[0];
  // d_in[1] = text_lengths: unused by the reference
  const float* emb    = (const float*)d_in[2];
  const float* W_ih   = (const float*)d_in[3];
  const float* W_hh   = (const float*)d_in[4];
  const float* b_ih   = (const float*)d_in[5];
  const float* b_hh   = (const float*)d_in[6];
  const float* W_word = (const float*)d_in[7];
  const float* b_word = (const float*)d_in[8];
  const float* w_proj = (const float*)d_in[9];
  const float* dec_W  = (const float*)d_in[10];
  const float* dec_b  = (const float*)d_in[11];
  float* out = (float*)d_out;

  char* ws = (char*)d_ws;
  float* xproj  = (float*)ws;
  float* states = (float*)(ws + STATES_OFF);
  ull*   h_buf  = (ull*)(ws + HBUF_OFF);
  float* part   = (float*)(ws + PART_OFF);
  float* poolP  = (float*)(ws + POOLP_OFF);
  float* ml     = (float*)(ws + ML_OFF);

  // tags must start invalid each launch (prevents cross-replay tag collision)
  hipMemsetAsync(h_buf, 0, HBUF_BYTES, stream);

  // 1) x-projection for all timesteps (parallel GEMM, 67 GFLOP)
  xproj_gemm<<<dim3(250, 16), 256, 0, stream>>>(idx, emb, W_ih, b_ih, b_hh, xproj);

  // 2) recurrence (persistent cooperative, proven 256-block shape)
  void* args[] = {(void*)&xproj, (void*)&W_hh, (void*)&states, (void*)&h_buf};
  hipLaunchCooperativeKernel(lstm_persistent, dim3(NBLOCKS), dim3(NTHREADS), args, 0, stream);

  // 3) attention scores + 4) two-phase softmax/pool + decode
  attn_gemm<<<dim3(250, 4), 256, 0, stream>>>(states, W_word, b_word, w_proj, part);
  pool_partial<<<BATCH * NSLICE, 256, 0, stream>>>(part, states, poolP, ml);
  pool_merge_decode<<<BATCH, 256, 0, stream>>>(poolP, ml, dec_W, dec_b, out);
}